// Round 3
// baseline (752.325 us; speedup 1.0000x reference)
//
#include <hip/hip_runtime.h>
#include <hip/hip_bf16.h>
#include <hip/hip_fp16.h>
#include <hip/hip_cooperative_groups.h>

// SparseConvTranspose: gather-MFMA-scatter.
// Round 7: main kernel measured AT the atomic-rate wall (43.2M half2 atomics
// / 143us = 302 ops/ns ~= 98% of 128 TCC channels x 2.4GHz). Inner loop is
// left untouched. This round attacks the OTHER 111us: prep + h2 + ~80us of
// inter-kernel launch gaps, by fusing all three stages into one cooperative
// kernel (grid.sync x2, 2025 blocks <= 2048 co-resident, VGPR<=64 enforced).

namespace cg = cooperative_groups;

using short8  = __attribute__((ext_vector_type(8))) short;
using floatx4 = __attribute__((ext_vector_type(4))) float;
using f32x4   = __attribute__((ext_vector_type(4))) float;
using i32x4   = __attribute__((ext_vector_type(4))) int;

constexpr int KOFF = 27;
constexpr int NIN  = 100000;
constexpr int NOUT = 400000;
constexpr int CIN  = 64;
constexpr int COUT = 32;
constexpr int MSGS = NIN;
constexpr int TILES = MSGS / 16;          // 6250
constexpr int WPB   = 4;                  // waves per block

// cooperative-fused geometry: 75 blocks per k * 27 k = 2025 blocks (<2048
// co-resident at 8 blocks/CU), 300 waves per k.
constexpr int CBLK_PER_K = 75;
constexpr int COOP_BLOCKS = CBLK_PER_K * KOFF;   // 2025
constexpr int CWSTRIDE = CBLK_PER_K * WPB;       // 300
constexpr int CTHREADS = COOP_BLOCKS * 256;      // 518400

// legacy 3-kernel geometry (fallback)
constexpr int BLK_PER_K = 128;
constexpr int WSTRIDE = BLK_PER_K * WPB;  // 512

constexpr size_t ACC_BYTES   = (size_t)NOUT * COUT * 2;   // 25.6 MB fp16 accum
constexpr size_t FEATS_BYTES = (size_t)NIN * CIN * 2;     // 12.8 MB bf16 feats

constexpr int CVT_BLOCKS  = (NIN * CIN / 8) / 256;        // 3125
constexpr int ZERO_BLOCKS = (int)(ACC_BYTES / 16) / 256;  // 6250

__device__ __forceinline__ short f2bf(float f) {
    union { float f; unsigned u; } v; v.f = f;
    unsigned r = v.u + 0x7fff + ((v.u >> 16) & 1u);
    return (short)(r >> 16);
}

// ---------------- fused: prep -> gather-MFMA-scatter -> convert ------------
__global__ __launch_bounds__(256, 8) void spconv_fused_kernel(
    const float* __restrict__ feats_f32,
    ushort*      __restrict__ feats_bf,
    const float* __restrict__ weight,
    const int*   __restrict__ in_map,
    const int*   __restrict__ out_map,
    __half2*     __restrict__ accum,
    float*       __restrict__ out)
{
    cg::grid_group grid = cg::this_grid();
    const int gtid = blockIdx.x * 256 + threadIdx.x;

    // ---- phase 0: feats f32->bf16 convert + accum zero (grid-stride) ----
    for (int t = gtid; t < NIN * CIN / 8; t += CTHREADS) {
        const f32x4* p = (const f32x4*)(feats_f32 + (size_t)t * 8);
        f32x4 lo = __builtin_nontemporal_load(p);
        f32x4 hi = __builtin_nontemporal_load(p + 1);
        short8 v;
        v[0]=f2bf(lo[0]); v[1]=f2bf(lo[1]); v[2]=f2bf(lo[2]); v[3]=f2bf(lo[3]);
        v[4]=f2bf(hi[0]); v[5]=f2bf(hi[1]); v[6]=f2bf(hi[2]); v[7]=f2bf(hi[3]);
        *(short8*)(feats_bf + (size_t)t * 8) = v;
    }
    {
        f32x4* accz = (f32x4*)accum;
        f32x4 z = {0.f, 0.f, 0.f, 0.f};
        for (int t = gtid; t < (int)(ACC_BYTES / 16); t += CTHREADS)
            __builtin_nontemporal_store(z, accz + t);
    }
    grid.sync();

    // ---- phase 1: pipelined gather-MFMA-scatter (inner loop = round 6) ----
    {
        const int k    = blockIdx.x / CBLK_PER_K;
        const int bx   = blockIdx.x % CBLK_PER_K;
        const int wave = threadIdx.x >> 6;
        const int lane = threadIdx.x & 63;
        const int col  = lane & 15;
        const int quad = lane >> 4;
        const int kM   = k * MSGS;

        const float* Wk = weight + k * (CIN * COUT);
        short8 bfr[2][2];
        #pragma unroll
        for (int s = 0; s < 2; ++s)
            #pragma unroll
            for (int t = 0; t < 2; ++t)
                #pragma unroll
                for (int j = 0; j < 8; ++j)
                    bfr[s][t][j] = f2bf(Wk[(s * 32 + quad * 8 + j) * COUT + 2 * col + t]);

        auto load_maps = [&](int t, int& inr, i32x4& orow) {
            const int tt = (t < TILES) ? t : (TILES - 1);
            const int mb = kM + tt * 16;
            inr  = __builtin_nontemporal_load(in_map + mb + col);
            orow = __builtin_nontemporal_load((const i32x4*)(out_map + mb + quad * 4));
        };
        auto load_feats = [&](int inr, short8& a0, short8& a1) {
            const ushort* ar = feats_bf + inr * CIN;
            a0 = *(const short8*)(ar + quad * 8);
            a1 = *(const short8*)(ar + 32 + quad * 8);
        };

        const int t0 = bx * WPB + wave;

        int inrA; i32x4 orowA; load_maps(t0,                inrA, orowA);
        int inrB; i32x4 orowB; load_maps(t0 +     CWSTRIDE, inrB, orowB);
        int inrC; i32x4 orowC; load_maps(t0 + 2 * CWSTRIDE, inrC, orowC);
        short8 a0A, a1A; load_feats(inrA, a0A, a1A);
        short8 a0B, a1B; load_feats(inrB, a0B, a1B);

        for (int t = t0; t < TILES; t += CWSTRIDE) {
            int inrD; i32x4 orowD;
            load_maps(t + 3 * CWSTRIDE, inrD, orowD);
            short8 a0C, a1C;
            load_feats(inrC, a0C, a1C);

            floatx4 acc0 = {0.f, 0.f, 0.f, 0.f};
            floatx4 acc1 = {0.f, 0.f, 0.f, 0.f};
            acc0 = __builtin_amdgcn_mfma_f32_16x16x32_bf16(a0A, bfr[0][0], acc0, 0, 0, 0);
            acc1 = __builtin_amdgcn_mfma_f32_16x16x32_bf16(a0A, bfr[0][1], acc1, 0, 0, 0);
            acc0 = __builtin_amdgcn_mfma_f32_16x16x32_bf16(a1A, bfr[1][0], acc0, 0, 0, 0);
            acc1 = __builtin_amdgcn_mfma_f32_16x16x32_bf16(a1A, bfr[1][1], acc1, 0, 0, 0);

            const int orr[4] = {orowA[0], orowA[1], orowA[2], orowA[3]};
            #pragma unroll
            for (int i = 0; i < 4; ++i) {
                __half2 h = __floats2half2_rn(acc0[i], acc1[i]);
                unsafeAtomicAdd(accum + orr[i] * 16 + col, h);
            }

            inrA = inrB; a0A = a0B; a1A = a1B; orowA = orowB;
            inrB = inrC; a0B = a0C; a1B = a1C; orowB = orowC;
            inrC = inrD; orowC = orowD;
        }
    }
    grid.sync();

    // ---- phase 2: fp16 accum -> f32 out (grid-stride) ----
    for (int t = gtid; t < NOUT * 16 / 4; t += CTHREADS) {
        const __half2* p = accum + (size_t)t * 4;
        float2 f0 = __half22float2(p[0]);
        float2 f1 = __half22float2(p[1]);
        float2 f2 = __half22float2(p[2]);
        float2 f3 = __half22float2(p[3]);
        f32x4* o = (f32x4*)out + (size_t)t * 2;
        f32x4 o0 = {f0.x, f0.y, f1.x, f1.y};
        f32x4 o1 = {f2.x, f2.y, f3.x, f3.y};
        __builtin_nontemporal_store(o0, o);
        __builtin_nontemporal_store(o1, o + 1);
    }
}

// ================= legacy 3-kernel path (fallback) =========================

__global__ __launch_bounds__(256) void prep_kernel(
    const float* __restrict__ f, ushort* __restrict__ b, f32x4* __restrict__ accz)
{
    if (blockIdx.x < CVT_BLOCKS) {
        const int t = blockIdx.x * 256 + threadIdx.x;
        const f32x4* p = (const f32x4*)(f + (size_t)t * 8);
        f32x4 lo = __builtin_nontemporal_load(p);
        f32x4 hi = __builtin_nontemporal_load(p + 1);
        short8 v;
        v[0]=f2bf(lo[0]); v[1]=f2bf(lo[1]); v[2]=f2bf(lo[2]); v[3]=f2bf(lo[3]);
        v[4]=f2bf(hi[0]); v[5]=f2bf(hi[1]); v[6]=f2bf(hi[2]); v[7]=f2bf(hi[3]);
        *(short8*)(b + (size_t)t * 8) = v;
    } else {
        const int t = (blockIdx.x - CVT_BLOCKS) * 256 + threadIdx.x;
        f32x4 z = {0.f, 0.f, 0.f, 0.f};
        __builtin_nontemporal_store(z, accz + t);
    }
}

__global__ __launch_bounds__(256) void spconv_pipe_kernel(
    const ushort* __restrict__ feats_bf,
    const float*  __restrict__ weight,
    const int*    __restrict__ in_map,
    const int*    __restrict__ out_map,
    __half2*      __restrict__ accum)
{
    const int k    = blockIdx.y;
    const int wave = threadIdx.x >> 6;
    const int lane = threadIdx.x & 63;
    const int col  = lane & 15;
    const int quad = lane >> 4;
    const int kM   = k * MSGS;

    const float* Wk = weight + k * (CIN * COUT);
    short8 bfr[2][2];
    #pragma unroll
    for (int s = 0; s < 2; ++s)
        #pragma unroll
        for (int t = 0; t < 2; ++t)
            #pragma unroll
            for (int j = 0; j < 8; ++j)
                bfr[s][t][j] = f2bf(Wk[(s * 32 + quad * 8 + j) * COUT + 2 * col + t]);

    auto load_maps = [&](int t, int& inr, i32x4& orow) {
        const int tt = (t < TILES) ? t : (TILES - 1);
        const int mb = kM + tt * 16;
        inr  = __builtin_nontemporal_load(in_map + mb + col);
        orow = __builtin_nontemporal_load((const i32x4*)(out_map + mb + quad * 4));
    };
    auto load_feats = [&](int inr, short8& a0, short8& a1) {
        const ushort* ar = feats_bf + inr * CIN;
        a0 = *(const short8*)(ar + quad * 8);
        a1 = *(const short8*)(ar + 32 + quad * 8);
    };

    const int t0 = blockIdx.x * WPB + wave;

    int inrA; i32x4 orowA; load_maps(t0,               inrA, orowA);
    int inrB; i32x4 orowB; load_maps(t0 +     WSTRIDE, inrB, orowB);
    int inrC; i32x4 orowC; load_maps(t0 + 2 * WSTRIDE, inrC, orowC);
    short8 a0A, a1A; load_feats(inrA, a0A, a1A);
    short8 a0B, a1B; load_feats(inrB, a0B, a1B);

    for (int t = t0; t < TILES; t += WSTRIDE) {
        int inrD; i32x4 orowD;
        load_maps(t + 3 * WSTRIDE, inrD, orowD);
        short8 a0C, a1C;
        load_feats(inrC, a0C, a1C);

        floatx4 acc0 = {0.f, 0.f, 0.f, 0.f};
        floatx4 acc1 = {0.f, 0.f, 0.f, 0.f};
        acc0 = __builtin_amdgcn_mfma_f32_16x16x32_bf16(a0A, bfr[0][0], acc0, 0, 0, 0);
        acc1 = __builtin_amdgcn_mfma_f32_16x16x32_bf16(a0A, bfr[0][1], acc1, 0, 0, 0);
        acc0 = __builtin_amdgcn_mfma_f32_16x16x32_bf16(a1A, bfr[1][0], acc0, 0, 0, 0);
        acc1 = __builtin_amdgcn_mfma_f32_16x16x32_bf16(a1A, bfr[1][1], acc1, 0, 0, 0);

        const int orr[4] = {orowA[0], orowA[1], orowA[2], orowA[3]};
        #pragma unroll
        for (int i = 0; i < 4; ++i) {
            __half2 h = __floats2half2_rn(acc0[i], acc1[i]);
            unsafeAtomicAdd(accum + orr[i] * 16 + col, h);
        }

        inrA = inrB; a0A = a0B; a1A = a1B; orowA = orowB;
        inrB = inrC; a0B = a0C; a1B = a1C; orowB = orowC;
        inrC = inrD; orowC = orowD;
    }
}

__global__ __launch_bounds__(256) void spconv_fp16acc_f32feats_kernel(
    const float*  __restrict__ feats_f32,
    const float*  __restrict__ weight,
    const int*    __restrict__ in_map,
    const int*    __restrict__ out_map,
    __half2*      __restrict__ accum)
{
    const int k    = blockIdx.y;
    const int wave = threadIdx.x >> 6;
    const int lane = threadIdx.x & 63;
    const int col  = lane & 15;
    const int quad = lane >> 4;
    const int tile = blockIdx.x * WPB + wave;
    if (tile >= TILES) return;
    const int m0 = tile * 16;
    const long long mapbase = (long long)k * MSGS;

    const int in_row = in_map[mapbase + m0 + col];
    int orow[4];
    #pragma unroll
    for (int i = 0; i < 4; ++i) orow[i] = out_map[mapbase + m0 + quad * 4 + i];

    const float* Wk = weight + k * (CIN * COUT);
    short8 bfr[2][2];
    #pragma unroll
    for (int s = 0; s < 2; ++s)
        #pragma unroll
        for (int t = 0; t < 2; ++t)
            #pragma unroll
            for (int j = 0; j < 8; ++j)
                bfr[s][t][j] = f2bf(Wk[(s * 32 + quad * 8 + j) * COUT + 2 * col + t]);

    const float* ar = feats_f32 + (long long)in_row * CIN + quad * 8;
    const float4* p0 = (const float4*)ar;
    const float4* p1 = (const float4*)(ar + 32);
    float4 l0 = p0[0], h0 = p0[1], l1 = p1[0], h1 = p1[1];
    short8 a0, a1;
    a0[0]=f2bf(l0.x); a0[1]=f2bf(l0.y); a0[2]=f2bf(l0.z); a0[3]=f2bf(l0.w);
    a0[4]=f2bf(h0.x); a0[5]=f2bf(h0.y); a0[6]=f2bf(h0.z); a0[7]=f2bf(h0.w);
    a1[0]=f2bf(l1.x); a1[1]=f2bf(l1.y); a1[2]=f2bf(l1.z); a1[3]=f2bf(l1.w);
    a1[4]=f2bf(h1.x); a1[5]=f2bf(h1.y); a1[6]=f2bf(h1.z); a1[7]=f2bf(h1.w);

    floatx4 acc0 = {0.f, 0.f, 0.f, 0.f};
    floatx4 acc1 = {0.f, 0.f, 0.f, 0.f};
    acc0 = __builtin_amdgcn_mfma_f32_16x16x32_bf16(a0, bfr[0][0], acc0, 0, 0, 0);
    acc1 = __builtin_amdgcn_mfma_f32_16x16x32_bf16(a0, bfr[0][1], acc1, 0, 0, 0);
    acc0 = __builtin_amdgcn_mfma_f32_16x16x32_bf16(a1, bfr[1][0], acc0, 0, 0, 0);
    acc1 = __builtin_amdgcn_mfma_f32_16x16x32_bf16(a1, bfr[1][1], acc1, 0, 0, 0);

    #pragma unroll
    for (int i = 0; i < 4; ++i) {
        __half2 h = __floats2half2_rn(acc0[i], acc1[i]);
        unsafeAtomicAdd(accum + (long long)orow[i] * 16 + col, h);
    }
}

__global__ __launch_bounds__(256) void spconv_f32atomic_kernel(
    const float* __restrict__ feats,
    const float* __restrict__ weight,
    const int*   __restrict__ in_map,
    const int*   __restrict__ out_map,
    float*       __restrict__ out)
{
    const int k    = blockIdx.y;
    const int wave = threadIdx.x >> 6;
    const int lane = threadIdx.x & 63;
    const int col  = lane & 15;
    const int quad = lane >> 4;
    const int tile = blockIdx.x * WPB + wave;
    if (tile >= TILES) return;
    const int m0 = tile * 16;
    const long long mapbase = (long long)k * MSGS;

    const float* Wk = weight + k * (CIN * COUT);
    short8 bfr[2][2];
    #pragma unroll
    for (int s = 0; s < 2; ++s)
        #pragma unroll
        for (int t = 0; t < 2; ++t)
            #pragma unroll
            for (int j = 0; j < 8; ++j)
                bfr[s][t][j] = f2bf(Wk[(s * 32 + quad * 8 + j) * COUT + t * 16 + col]);

    const int in_row = in_map[mapbase + m0 + col];
    const float* arow = feats + (long long)in_row * CIN + quad * 8;

    floatx4 acc0 = {0.f, 0.f, 0.f, 0.f};
    floatx4 acc1 = {0.f, 0.f, 0.f, 0.f};
    #pragma unroll
    for (int s = 0; s < 2; ++s) {
        const float4* p = (const float4*)(arow + s * 32);
        float4 lo = p[0], hi = p[1];
        short8 a;
        a[0]=f2bf(lo.x); a[1]=f2bf(lo.y); a[2]=f2bf(lo.z); a[3]=f2bf(lo.w);
        a[4]=f2bf(hi.x); a[5]=f2bf(hi.y); a[6]=f2bf(hi.z); a[7]=f2bf(hi.w);
        acc0 = __builtin_amdgcn_mfma_f32_16x16x32_bf16(a, bfr[s][0], acc0, 0, 0, 0);
        acc1 = __builtin_amdgcn_mfma_f32_16x16x32_bf16(a, bfr[s][1], acc1, 0, 0, 0);
    }
    #pragma unroll
    for (int i = 0; i < 4; ++i) {
        const int orow = out_map[mapbase + m0 + quad * 4 + i];
        float* po = out + (long long)orow * COUT;
        atomicAdd(po + col,      acc0[i]);
        atomicAdd(po + col + 16, acc1[i]);
    }
}

__global__ __launch_bounds__(256) void h2_to_f32_kernel(
    const __half2* __restrict__ acc, float* __restrict__ out)
{
    const int t = blockIdx.x * blockDim.x + threadIdx.x;
    const __half2* p = acc + (size_t)t * 4;
    float2 f0 = __half22float2(p[0]);
    float2 f1 = __half22float2(p[1]);
    float2 f2 = __half22float2(p[2]);
    float2 f3 = __half22float2(p[3]);
    f32x4* o = (f32x4*)out + (size_t)t * 2;
    f32x4 o0 = {f0.x, f0.y, f1.x, f1.y};
    f32x4 o1 = {f2.x, f2.y, f3.x, f3.y};
    __builtin_nontemporal_store(o0, o);
    __builtin_nontemporal_store(o1, o + 1);
}

extern "C" void kernel_launch(void* const* d_in, const int* in_sizes, int n_in,
                              void* d_out, int out_size, void* d_ws, size_t ws_size,
                              hipStream_t stream) {
    const float* feats   = (const float*)d_in[0];
    const float* weight  = (const float*)d_in[1];
    const int*   in_map  = (const int*)d_in[2];
    const int*   out_map = (const int*)d_in[3];
    float*       out     = (float*)d_out;

    if (ws_size >= ACC_BYTES + FEATS_BYTES) {
        __half2* accum    = (__half2*)d_ws;
        ushort*  feats_bf = (ushort*)((char*)d_ws + ACC_BYTES);

        void* args[] = {(void*)&feats, (void*)&feats_bf, (void*)&weight,
                        (void*)&in_map, (void*)&out_map, (void*)&accum,
                        (void*)&out};
        hipError_t e = hipLaunchCooperativeKernel(
            (const void*)spconv_fused_kernel, dim3(COOP_BLOCKS), dim3(256),
            args, 0, stream);
        if (e != hipSuccess) {
            // fallback: 3-kernel path (identical math)
            prep_kernel<<<CVT_BLOCKS + ZERO_BLOCKS, 256, 0, stream>>>(
                feats, feats_bf, (f32x4*)accum);
            spconv_pipe_kernel<<<dim3(BLK_PER_K, KOFF), 256, 0, stream>>>(
                feats_bf, weight, in_map, out_map, accum);
            h2_to_f32_kernel<<<(NOUT * 16 / 4) / 256, 256, 0, stream>>>(accum, out);
        }
    } else if (ws_size >= ACC_BYTES) {
        __half2* accum = (__half2*)d_ws;
        hipMemsetAsync(accum, 0, ACC_BYTES, stream);
        spconv_fp16acc_f32feats_kernel<<<dim3((TILES + WPB - 1) / WPB, KOFF), 256, 0, stream>>>(
            feats, weight, in_map, out_map, accum);
        h2_to_f32_kernel<<<(NOUT * 16 / 4) / 256, 256, 0, stream>>>(accum, out);
    } else {
        hipMemsetAsync(d_out, 0, (size_t)out_size * sizeof(float), stream);
        spconv_f32atomic_kernel<<<dim3((TILES + WPB - 1) / WPB, KOFF), 256, 0, stream>>>(
            feats, weight, in_map, out_map, out);
    }
}

// Round 5
// 258.779 us; speedup vs baseline: 2.9072x; 2.9072x over previous
//
#include <hip/hip_runtime.h>
#include <hip/hip_bf16.h>
#include <hip/hip_fp16.h>

// SparseConvTranspose: gather-MFMA-scatter.
// Round 9: safe consolidation. Coop fusion abandoned (r7: launch_bounds
// register crush; r8: likely grid.sync deadlock/hang). Analysis across r2/r7:
// ~84us/iter is fixed harness overhead; main kernel (143us) sits at the
// device atomic-rate wall (43.2M pk-f16 atomics -> 302 ops/ns ~= 98% of
// 128 channels x 2.4GHz). This round shaves the aux budget: feats are
// gathered as f32 and converted in-register (main kernel has VALU/BW slack),
// so prep collapses to a single 25.6MB hipMemsetAsync. 2 custom kernels.

using short8  = __attribute__((ext_vector_type(8))) short;
using floatx4 = __attribute__((ext_vector_type(4))) float;
using f32x4   = __attribute__((ext_vector_type(4))) float;
using i32x4   = __attribute__((ext_vector_type(4))) int;

constexpr int KOFF = 27;
constexpr int NIN  = 100000;
constexpr int NOUT = 400000;
constexpr int CIN  = 64;
constexpr int COUT = 32;
constexpr int MSGS = NIN;
constexpr int TILES = MSGS / 16;          // 6250
constexpr int WPB   = 4;                  // waves per block
constexpr int BLK_PER_K = 128;            // proven at the atomic wall (r6)
constexpr int WSTRIDE = BLK_PER_K * WPB;  // 512 waves per k

constexpr size_t ACC_BYTES = (size_t)NOUT * COUT * 2;     // 25.6 MB fp16 accum

__device__ __forceinline__ short f2bf(float f) {
    union { float f; unsigned u; } v; v.f = f;
    unsigned r = v.u + 0x7fff + ((v.u >> 16) & 1u);
    return (short)(r >> 16);
}

// ---------------- main: pipelined gather(f32)-MFMA-scatter -----------------
// Pipeline: maps 3 ahead; feats raw-f32 1 stage + converted 1 stage.
// Per message row (16 lanes x 4 rows): 16 half2 atomics = 64B (minimal
// encoding; no wider packed-f16 atomic exists on gfx950).
__global__ __launch_bounds__(256) void spconv_pipe_f32_kernel(
    const float* __restrict__ feats,
    const float* __restrict__ weight,
    const int*   __restrict__ in_map,
    const int*   __restrict__ out_map,
    __half2*     __restrict__ accum)
{
    const int k    = blockIdx.y;
    const int wave = threadIdx.x >> 6;
    const int lane = threadIdx.x & 63;
    const int col  = lane & 15;
    const int quad = lane >> 4;
    const int kM   = k * MSGS;   // < 2.7M, fits int32

    // B fragments once per wave: bfr[s][t][j] = W[k][s*32+quad*8+j][2*col+t]
    const float* Wk = weight + k * (CIN * COUT);
    short8 bfr[2][2];
    #pragma unroll
    for (int s = 0; s < 2; ++s)
        #pragma unroll
        for (int t = 0; t < 2; ++t)
            #pragma unroll
            for (int j = 0; j < 8; ++j)
                bfr[s][t][j] = f2bf(Wk[(s * 32 + quad * 8 + j) * COUT + 2 * col + t]);

    auto load_maps = [&](int t, int& inr, i32x4& orow) {
        const int tt = (t < TILES) ? t : (TILES - 1);
        const int mb = kM + tt * 16;
        inr  = __builtin_nontemporal_load(in_map + mb + col);
        orow = __builtin_nontemporal_load((const i32x4*)(out_map + mb + quad * 4));
    };
    auto load_raw = [&](int inr, f32x4* r) {
        const float* ar = feats + (long long)inr * CIN + quad * 8;
        r[0] = *(const f32x4*)(ar);
        r[1] = *(const f32x4*)(ar + 4);
        r[2] = *(const f32x4*)(ar + 32);
        r[3] = *(const f32x4*)(ar + 36);
    };
    auto cvt = [&](const f32x4* r, short8& a0, short8& a1) {
        #pragma unroll
        for (int j = 0; j < 4; ++j) { a0[j] = f2bf(r[0][j]); a0[4+j] = f2bf(r[1][j]); }
        #pragma unroll
        for (int j = 0; j < 4; ++j) { a1[j] = f2bf(r[2][j]); a1[4+j] = f2bf(r[3][j]); }
    };

    const int t0 = blockIdx.x * WPB + wave;

    // pipeline state: maps for t,t+W,t+2W; feats converted for t, raw for t+W
    int inrA; i32x4 orowA; load_maps(t0,               inrA, orowA);
    int inrB; i32x4 orowB; load_maps(t0 +     WSTRIDE, inrB, orowB);
    int inrC; i32x4 orowC; load_maps(t0 + 2 * WSTRIDE, inrC, orowC);
    f32x4 rawA[4]; load_raw(inrA, rawA);
    short8 a0A, a1A; cvt(rawA, a0A, a1A);
    f32x4 rawB[4]; load_raw(inrB, rawB);

    for (int t = t0; t < TILES; t += WSTRIDE) {
        // stage 4: maps for t+3W
        int inrD; i32x4 orowD;
        load_maps(t + 3 * WSTRIDE, inrD, orowD);
        // stage 3: issue raw feats loads for t+2W (in flight this iteration)
        f32x4 rawC[4];
        load_raw(inrC, rawC);

        // stage 1: compute + scatter current tile
        floatx4 acc0 = {0.f, 0.f, 0.f, 0.f};
        floatx4 acc1 = {0.f, 0.f, 0.f, 0.f};
        acc0 = __builtin_amdgcn_mfma_f32_16x16x32_bf16(a0A, bfr[0][0], acc0, 0, 0, 0);
        acc1 = __builtin_amdgcn_mfma_f32_16x16x32_bf16(a0A, bfr[0][1], acc1, 0, 0, 0);
        acc0 = __builtin_amdgcn_mfma_f32_16x16x32_bf16(a1A, bfr[1][0], acc0, 0, 0, 0);
        acc1 = __builtin_amdgcn_mfma_f32_16x16x32_bf16(a1A, bfr[1][1], acc1, 0, 0, 0);

        const int orr[4] = {orowA[0], orowA[1], orowA[2], orowA[3]};
        #pragma unroll
        for (int i = 0; i < 4; ++i) {
            __half2 h = __floats2half2_rn(acc0[i], acc1[i]);
            unsafeAtomicAdd(accum + orr[i] * 16 + col, h);
        }

        // stage 2: convert raw t+W -> fragments for next iteration
        cvt(rawB, a0A, a1A);

        // rotate pipeline registers
        #pragma unroll
        for (int i = 0; i < 4; ++i) rawB[i] = rawC[i];
        orowA = orowB; orowB = orowC; orowC = orowD;
        inrC = inrD;
    }
}

// ---------------- last-resort fallback: f32 atomics to d_out ---------------
__global__ __launch_bounds__(256) void spconv_f32atomic_kernel(
    const float* __restrict__ feats,
    const float* __restrict__ weight,
    const int*   __restrict__ in_map,
    const int*   __restrict__ out_map,
    float*       __restrict__ out)
{
    const int k    = blockIdx.y;
    const int wave = threadIdx.x >> 6;
    const int lane = threadIdx.x & 63;
    const int col  = lane & 15;
    const int quad = lane >> 4;
    const int tile = blockIdx.x * WPB + wave;
    if (tile >= TILES) return;
    const int m0 = tile * 16;
    const long long mapbase = (long long)k * MSGS;

    const float* Wk = weight + k * (CIN * COUT);
    short8 bfr[2][2];
    #pragma unroll
    for (int s = 0; s < 2; ++s)
        #pragma unroll
        for (int t = 0; t < 2; ++t)
            #pragma unroll
            for (int j = 0; j < 8; ++j)
                bfr[s][t][j] = f2bf(Wk[(s * 32 + quad * 8 + j) * COUT + t * 16 + col]);

    const int in_row = in_map[mapbase + m0 + col];
    const float* arow = feats + (long long)in_row * CIN + quad * 8;

    floatx4 acc0 = {0.f, 0.f, 0.f, 0.f};
    floatx4 acc1 = {0.f, 0.f, 0.f, 0.f};
    #pragma unroll
    for (int s = 0; s < 2; ++s) {
        const float4* p = (const float4*)(arow + s * 32);
        float4 lo = p[0], hi = p[1];
        short8 a;
        a[0]=f2bf(lo.x); a[1]=f2bf(lo.y); a[2]=f2bf(lo.z); a[3]=f2bf(lo.w);
        a[4]=f2bf(hi.x); a[5]=f2bf(hi.y); a[6]=f2bf(hi.z); a[7]=f2bf(hi.w);
        acc0 = __builtin_amdgcn_mfma_f32_16x16x32_bf16(a, bfr[s][0], acc0, 0, 0, 0);
        acc1 = __builtin_amdgcn_mfma_f32_16x16x32_bf16(a, bfr[s][1], acc1, 0, 0, 0);
    }
    #pragma unroll
    for (int i = 0; i < 4; ++i) {
        const int orow = out_map[mapbase + m0 + quad * 4 + i];
        float* po = out + (long long)orow * COUT;
        atomicAdd(po + col,      acc0[i]);
        atomicAdd(po + col + 16, acc1[i]);
    }
}

// ---------------- fp16 accum -> f32 out ------------------------------------
__global__ __launch_bounds__(256) void h2_to_f32_kernel(
    const __half2* __restrict__ acc, float* __restrict__ out)
{
    const int t = blockIdx.x * blockDim.x + threadIdx.x;
    const __half2* p = acc + (size_t)t * 4;
    float2 f0 = __half22float2(p[0]);
    float2 f1 = __half22float2(p[1]);
    float2 f2 = __half22float2(p[2]);
    float2 f3 = __half22float2(p[3]);
    f32x4* o = (f32x4*)out + (size_t)t * 2;
    f32x4 o0 = {f0.x, f0.y, f1.x, f1.y};
    f32x4 o1 = {f2.x, f2.y, f3.x, f3.y};
    __builtin_nontemporal_store(o0, o);
    __builtin_nontemporal_store(o1, o + 1);
}

extern "C" void kernel_launch(void* const* d_in, const int* in_sizes, int n_in,
                              void* d_out, int out_size, void* d_ws, size_t ws_size,
                              hipStream_t stream) {
    const float* feats   = (const float*)d_in[0];
    const float* weight  = (const float*)d_in[1];
    const int*   in_map  = (const int*)d_in[2];
    const int*   out_map = (const int*)d_in[3];
    float*       out     = (float*)d_out;

    if (ws_size >= ACC_BYTES) {
        __half2* accum = (__half2*)d_ws;
        hipMemsetAsync(accum, 0, ACC_BYTES, stream);
        spconv_pipe_f32_kernel<<<dim3(BLK_PER_K, KOFF), 256, 0, stream>>>(
            feats, weight, in_map, out_map, accum);
        h2_to_f32_kernel<<<(NOUT * 16 / 4) / 256, 256, 0, stream>>>(accum, out);
    } else {
        hipMemsetAsync(d_out, 0, (size_t)out_size * sizeof(float), stream);
        spconv_f32atomic_kernel<<<dim3((TILES + WPB - 1) / WPB, KOFF), 256, 0, stream>>>(
            feats, weight, in_map, out_map, out);
    }
}

// Round 6
// 253.426 us; speedup vs baseline: 2.9686x; 1.0211x over previous
//
#include <hip/hip_runtime.h>
#include <hip/hip_bf16.h>
#include <hip/hip_fp16.h>

// SparseConvTranspose: gather-MFMA-scatter.
// Round 10: revert to the proven round-6 configuration (254.2us). Round-9's
// f32-gather test established that the main kernel's wall is TCC channel
// throughput SHARED between atomics and fetch: bf16 staging (FETCH 134MB)
// lets the 43.2M pk-f16 atomics run at 302 ops/ns = 98% of the 128-channel
// x 2.4GHz ceiling (floor 140.6us; measured 143us). Budget: main 143 +
// prep ~12 + h2 ~15 + ~84 fixed harness overhead ~= 254us total. This is
// the roofline for this scatter scheme.

using short8  = __attribute__((ext_vector_type(8))) short;
using floatx4 = __attribute__((ext_vector_type(4))) float;
using f32x4   = __attribute__((ext_vector_type(4))) float;
using i32x4   = __attribute__((ext_vector_type(4))) int;

constexpr int KOFF = 27;
constexpr int NIN  = 100000;
constexpr int NOUT = 400000;
constexpr int CIN  = 64;
constexpr int COUT = 32;
constexpr int MSGS = NIN;
constexpr int TILES = MSGS / 16;          // 6250
constexpr int WPB   = 4;                  // waves per block
constexpr int BLK_PER_K = 128;            // persistent blocks per kernel offset
constexpr int WSTRIDE = BLK_PER_K * WPB;  // 512 waves per k

constexpr size_t ACC_BYTES   = (size_t)NOUT * COUT * 2;   // 25.6 MB fp16 accum
constexpr size_t FEATS_BYTES = (size_t)NIN * CIN * 2;     // 12.8 MB bf16 feats

constexpr int CVT_BLOCKS  = (NIN * CIN / 8) / 256;        // 3125
constexpr int ZERO_BLOCKS = (int)(ACC_BYTES / 16) / 256;  // 6250

__device__ __forceinline__ short f2bf(float f) {
    union { float f; unsigned u; } v; v.f = f;
    unsigned r = v.u + 0x7fff + ((v.u >> 16) & 1u);
    return (short)(r >> 16);
}

// ---------------- prep: feats f32->bf16 convert + accum zero ---------------
__global__ __launch_bounds__(256) void prep_kernel(
    const float* __restrict__ f, ushort* __restrict__ b, f32x4* __restrict__ accz)
{
    if (blockIdx.x < CVT_BLOCKS) {
        const int t = blockIdx.x * 256 + threadIdx.x;
        const f32x4* p = (const f32x4*)(f + (size_t)t * 8);
        f32x4 lo = __builtin_nontemporal_load(p);
        f32x4 hi = __builtin_nontemporal_load(p + 1);
        short8 v;
        v[0]=f2bf(lo[0]); v[1]=f2bf(lo[1]); v[2]=f2bf(lo[2]); v[3]=f2bf(lo[3]);
        v[4]=f2bf(hi[0]); v[5]=f2bf(hi[1]); v[6]=f2bf(hi[2]); v[7]=f2bf(hi[3]);
        *(short8*)(b + (size_t)t * 8) = v;
    } else {
        const int t = (blockIdx.x - CVT_BLOCKS) * 256 + threadIdx.x;
        f32x4 z = {0.f, 0.f, 0.f, 0.f};
        __builtin_nontemporal_store(z, accz + t);
    }
}

// ---------------- main: pipelined gather-MFMA-scatter ----------------------
__global__ __launch_bounds__(256) void spconv_pipe_kernel(
    const ushort* __restrict__ feats_bf,
    const float*  __restrict__ weight,
    const int*    __restrict__ in_map,
    const int*    __restrict__ out_map,
    __half2*      __restrict__ accum)
{
    const int k    = blockIdx.y;
    const int wave = threadIdx.x >> 6;
    const int lane = threadIdx.x & 63;
    const int col  = lane & 15;
    const int quad = lane >> 4;
    const int kM   = k * MSGS;

    const float* Wk = weight + k * (CIN * COUT);
    short8 bfr[2][2];
    #pragma unroll
    for (int s = 0; s < 2; ++s)
        #pragma unroll
        for (int t = 0; t < 2; ++t)
            #pragma unroll
            for (int j = 0; j < 8; ++j)
                bfr[s][t][j] = f2bf(Wk[(s * 32 + quad * 8 + j) * COUT + 2 * col + t]);

    auto load_maps = [&](int t, int& inr, i32x4& orow) {
        const int tt = (t < TILES) ? t : (TILES - 1);
        const int mb = kM + tt * 16;
        inr  = __builtin_nontemporal_load(in_map + mb + col);
        orow = __builtin_nontemporal_load((const i32x4*)(out_map + mb + quad * 4));
    };
    auto load_feats = [&](int inr, short8& a0, short8& a1) {
        const ushort* ar = feats_bf + inr * CIN;
        a0 = *(const short8*)(ar + quad * 8);
        a1 = *(const short8*)(ar + 32 + quad * 8);
    };

    const int t0 = blockIdx.x * WPB + wave;

    int inrA; i32x4 orowA; load_maps(t0,               inrA, orowA);
    int inrB; i32x4 orowB; load_maps(t0 +     WSTRIDE, inrB, orowB);
    int inrC; i32x4 orowC; load_maps(t0 + 2 * WSTRIDE, inrC, orowC);
    short8 a0A, a1A; load_feats(inrA, a0A, a1A);
    short8 a0B, a1B; load_feats(inrB, a0B, a1B);

    for (int t = t0; t < TILES; t += WSTRIDE) {
        int inrD; i32x4 orowD;
        load_maps(t + 3 * WSTRIDE, inrD, orowD);
        short8 a0C, a1C;
        load_feats(inrC, a0C, a1C);

        floatx4 acc0 = {0.f, 0.f, 0.f, 0.f};
        floatx4 acc1 = {0.f, 0.f, 0.f, 0.f};
        acc0 = __builtin_amdgcn_mfma_f32_16x16x32_bf16(a0A, bfr[0][0], acc0, 0, 0, 0);
        acc1 = __builtin_amdgcn_mfma_f32_16x16x32_bf16(a0A, bfr[0][1], acc1, 0, 0, 0);
        acc0 = __builtin_amdgcn_mfma_f32_16x16x32_bf16(a1A, bfr[1][0], acc0, 0, 0, 0);
        acc1 = __builtin_amdgcn_mfma_f32_16x16x32_bf16(a1A, bfr[1][1], acc1, 0, 0, 0);

        const int orr[4] = {orowA[0], orowA[1], orowA[2], orowA[3]};
        #pragma unroll
        for (int i = 0; i < 4; ++i) {
            __half2 h = __floats2half2_rn(acc0[i], acc1[i]);
            unsafeAtomicAdd(accum + orr[i] * 16 + col, h);
        }

        inrA = inrB; a0A = a0B; a1A = a1B; orowA = orowB;
        inrB = inrC; a0B = a0C; a1B = a1C; orowB = orowC;
        inrC = inrD; orowC = orowD;
    }
}

// ---------------- fallback (ws >= ACC only): fp16 atomics, f32 feats -------
__global__ __launch_bounds__(256) void spconv_fp16acc_f32feats_kernel(
    const float*  __restrict__ feats_f32,
    const float*  __restrict__ weight,
    const int*    __restrict__ in_map,
    const int*    __restrict__ out_map,
    __half2*      __restrict__ accum)
{
    const int k    = blockIdx.y;
    const int wave = threadIdx.x >> 6;
    const int lane = threadIdx.x & 63;
    const int col  = lane & 15;
    const int quad = lane >> 4;
    const int tile = blockIdx.x * WPB + wave;
    if (tile >= TILES) return;
    const int m0 = tile * 16;
    const long long mapbase = (long long)k * MSGS;

    const int in_row = in_map[mapbase + m0 + col];
    int orow[4];
    #pragma unroll
    for (int i = 0; i < 4; ++i) orow[i] = out_map[mapbase + m0 + quad * 4 + i];

    const float* Wk = weight + k * (CIN * COUT);
    short8 bfr[2][2];
    #pragma unroll
    for (int s = 0; s < 2; ++s)
        #pragma unroll
        for (int t = 0; t < 2; ++t)
            #pragma unroll
            for (int j = 0; j < 8; ++j)
                bfr[s][t][j] = f2bf(Wk[(s * 32 + quad * 8 + j) * COUT + 2 * col + t]);

    const float* ar = feats_f32 + (long long)in_row * CIN + quad * 8;
    const float4* p0 = (const float4*)ar;
    const float4* p1 = (const float4*)(ar + 32);
    float4 l0 = p0[0], h0 = p0[1], l1 = p1[0], h1 = p1[1];
    short8 a0, a1;
    a0[0]=f2bf(l0.x); a0[1]=f2bf(l0.y); a0[2]=f2bf(l0.z); a0[3]=f2bf(l0.w);
    a0[4]=f2bf(h0.x); a0[5]=f2bf(h0.y); a0[6]=f2bf(h0.z); a0[7]=f2bf(h0.w);
    a1[0]=f2bf(l1.x); a1[1]=f2bf(l1.y); a1[2]=f2bf(l1.z); a1[3]=f2bf(l1.w);
    a1[4]=f2bf(h1.x); a1[5]=f2bf(h1.y); a1[6]=f2bf(h1.z); a1[7]=f2bf(h1.w);

    floatx4 acc0 = {0.f, 0.f, 0.f, 0.f};
    floatx4 acc1 = {0.f, 0.f, 0.f, 0.f};
    acc0 = __builtin_amdgcn_mfma_f32_16x16x32_bf16(a0, bfr[0][0], acc0, 0, 0, 0);
    acc1 = __builtin_amdgcn_mfma_f32_16x16x32_bf16(a0, bfr[0][1], acc1, 0, 0, 0);
    acc0 = __builtin_amdgcn_mfma_f32_16x16x32_bf16(a1, bfr[1][0], acc0, 0, 0, 0);
    acc1 = __builtin_amdgcn_mfma_f32_16x16x32_bf16(a1, bfr[1][1], acc1, 0, 0, 0);

    #pragma unroll
    for (int i = 0; i < 4; ++i) {
        __half2 h = __floats2half2_rn(acc0[i], acc1[i]);
        unsafeAtomicAdd(accum + (long long)orow[i] * 16 + col, h);
    }
}

// ---------------- last-resort fallback: f32 atomics to d_out ---------------
__global__ __launch_bounds__(256) void spconv_f32atomic_kernel(
    const float* __restrict__ feats,
    const float* __restrict__ weight,
    const int*   __restrict__ in_map,
    const int*   __restrict__ out_map,
    float*       __restrict__ out)
{
    const int k    = blockIdx.y;
    const int wave = threadIdx.x >> 6;
    const int lane = threadIdx.x & 63;
    const int col  = lane & 15;
    const int quad = lane >> 4;
    const int tile = blockIdx.x * WPB + wave;
    if (tile >= TILES) return;
    const int m0 = tile * 16;
    const long long mapbase = (long long)k * MSGS;

    const float* Wk = weight + k * (CIN * COUT);
    short8 bfr[2][2];
    #pragma unroll
    for (int s = 0; s < 2; ++s)
        #pragma unroll
        for (int t = 0; t < 2; ++t)
            #pragma unroll
            for (int j = 0; j < 8; ++j)
                bfr[s][t][j] = f2bf(Wk[(s * 32 + quad * 8 + j) * COUT + t * 16 + col]);

    const int in_row = in_map[mapbase + m0 + col];
    const float* arow = feats + (long long)in_row * CIN + quad * 8;

    floatx4 acc0 = {0.f, 0.f, 0.f, 0.f};
    floatx4 acc1 = {0.f, 0.f, 0.f, 0.f};
    #pragma unroll
    for (int s = 0; s < 2; ++s) {
        const float4* p = (const float4*)(arow + s * 32);
        float4 lo = p[0], hi = p[1];
        short8 a;
        a[0]=f2bf(lo.x); a[1]=f2bf(lo.y); a[2]=f2bf(lo.z); a[3]=f2bf(lo.w);
        a[4]=f2bf(hi.x); a[5]=f2bf(hi.y); a[6]=f2bf(hi.z); a[7]=f2bf(hi.w);
        acc0 = __builtin_amdgcn_mfma_f32_16x16x32_bf16(a, bfr[s][0], acc0, 0, 0, 0);
        acc1 = __builtin_amdgcn_mfma_f32_16x16x32_bf16(a, bfr[s][1], acc1, 0, 0, 0);
    }
    #pragma unroll
    for (int i = 0; i < 4; ++i) {
        const int orow = out_map[mapbase + m0 + quad * 4 + i];
        float* po = out + (long long)orow * COUT;
        atomicAdd(po + col,      acc0[i]);
        atomicAdd(po + col + 16, acc1[i]);
    }
}

// ---------------- fp16 accum -> f32 out ------------------------------------
__global__ __launch_bounds__(256) void h2_to_f32_kernel(
    const __half2* __restrict__ acc, float* __restrict__ out)
{
    const int t = blockIdx.x * blockDim.x + threadIdx.x;
    const __half2* p = acc + (size_t)t * 4;
    float2 f0 = __half22float2(p[0]);
    float2 f1 = __half22float2(p[1]);
    float2 f2 = __half22float2(p[2]);
    float2 f3 = __half22float2(p[3]);
    f32x4* o = (f32x4*)out + (size_t)t * 2;
    f32x4 o0 = {f0.x, f0.y, f1.x, f1.y};
    f32x4 o1 = {f2.x, f2.y, f3.x, f3.y};
    __builtin_nontemporal_store(o0, o);
    __builtin_nontemporal_store(o1, o + 1);
}

extern "C" void kernel_launch(void* const* d_in, const int* in_sizes, int n_in,
                              void* d_out, int out_size, void* d_ws, size_t ws_size,
                              hipStream_t stream) {
    const float* feats   = (const float*)d_in[0];
    const float* weight  = (const float*)d_in[1];
    const int*   in_map  = (const int*)d_in[2];
    const int*   out_map = (const int*)d_in[3];
    float*       out     = (float*)d_out;

    if (ws_size >= ACC_BYTES + FEATS_BYTES) {
        __half2* accum    = (__half2*)d_ws;
        ushort*  feats_bf = (ushort*)((char*)d_ws + ACC_BYTES);

        prep_kernel<<<CVT_BLOCKS + ZERO_BLOCKS, 256, 0, stream>>>(
            feats, feats_bf, (f32x4*)accum);
        spconv_pipe_kernel<<<dim3(BLK_PER_K, KOFF), 256, 0, stream>>>(
            feats_bf, weight, in_map, out_map, accum);
        h2_to_f32_kernel<<<(NOUT * 16 / 4) / 256, 256, 0, stream>>>(accum, out);
    } else if (ws_size >= ACC_BYTES) {
        __half2* accum = (__half2*)d_ws;
        hipMemsetAsync(accum, 0, ACC_BYTES, stream);
        spconv_fp16acc_f32feats_kernel<<<dim3((TILES + WPB - 1) / WPB, KOFF), 256, 0, stream>>>(
            feats, weight, in_map, out_map, accum);
        h2_to_f32_kernel<<<(NOUT * 16 / 4) / 256, 256, 0, stream>>>(accum, out);
    } else {
        hipMemsetAsync(d_out, 0, (size_t)out_size * sizeof(float), stream);
        spconv_f32atomic_kernel<<<dim3((TILES + WPB - 1) / WPB, KOFF), 256, 0, stream>>>(
            feats, weight, in_map, out_map, out);
    }
}